// Round 18
// baseline (282.395 us; speedup 1.0000x reference)
//
#include <hip/hip_runtime.h>

#define NN 50000
#define NE 800000
#define NB 256
#define BNODES ((NN + NB - 1) / NB)  // 196 nodes per bucket
#define CAP 4096                     // bucket window capacity (mean 3125, +17 sigma)
#define BPART_BLKS ((NE + 8191) / 8192)          // 98
#define PREP_BLKS ((NN * 28 + 255) / 256)        // 5469
#define PACK_BLKS ((180224 + 255) / 256)         // 704
static constexpr float BN_EPS = 1e-5f;

typedef __attribute__((ext_vector_type(8))) short bf16x8;
typedef __attribute__((ext_vector_type(4))) float f32x4;

__device__ inline unsigned short f2bf(float f) {
  unsigned int u = __float_as_uint(f);
  return (unsigned short)((u + 0x7FFFu + ((u >> 16) & 1u)) >> 16);
}
__device__ inline float bf2f(unsigned int h) { return __uint_as_float(h << 16); }
__device__ inline void gl_lds16(const char* g, char* l) {
  __builtin_amdgcn_global_load_lds((const __attribute__((address_space(1))) void*)g,
                                   (__attribute__((address_space(3))) void*)l, 16, 0, 0);
}

// ========== fused front kernel: bpart | prep_x (vectorized) | pack_w | bnacc zero ==========
__device__ void dev_bpart(int bb, const int* __restrict__ src, const int* __restrict__ dst,
                          int* __restrict__ bcur, uint2* __restrict__ pairs) {
  __shared__ int cnt[NB], lbase[NB], lcur[NB];
  int t = threadIdx.x;
  cnt[t] = 0;
  __syncthreads();
  int e0 = bb * 8192 + t;
#pragma unroll
  for (int i = 0; i < 32; ++i) {
    int e = e0 + i * 256;
    if (e < NE) atomicAdd(&cnt[dst[e] / BNODES], 1);
  }
  __syncthreads();
  lbase[t] = cnt[t] ? (t * CAP + atomicAdd(&bcur[t], cnt[t])) : 0;
  lcur[t] = 0;
  __syncthreads();
#pragma unroll
  for (int i = 0; i < 32; ++i) {
    int e = e0 + i * 256;
    if (e < NE) {
      int d = dst[e];
      int b = d / BNODES;
      int p = atomicAdd(&lcur[b], 1);
      pairs[(size_t)lbase[b] + p] = uint2{(unsigned)src[e], (unsigned)d};
    }
  }
}

__global__ void k_front(const int* __restrict__ src, const int* __restrict__ dst,
                        int* __restrict__ bcur, uint2* __restrict__ pairs,
                        const float* __restrict__ x, unsigned int* __restrict__ xbu,
                        unsigned int* __restrict__ aggX,
                        const float* __restrict__ Wl1, const float* __restrict__ Wr1,
                        const float* __restrict__ Wl2, const float* __restrict__ Wr2,
                        const float* __restrict__ Wle, const float* __restrict__ Wre,
                        unsigned short* __restrict__ w1c, unsigned short* __restrict__ w2s,
                        unsigned short* __restrict__ w3s,
                        float* __restrict__ bnacc) {
  int b = blockIdx.x;
  if (b < BPART_BLKS) {
    dev_bpart(b, src, dst, bcur, pairs);
    return;
  }
  b -= BPART_BLKS;
  if (b < PREP_BLKS) {
    int i = b * 256 + threadIdx.x;
    if (i >= NN * 28) return;
    int r = i / 28, q = i - r * 28;
    if (q < 24) {  // xbu uint4 q: uints 4q..4q+3 = bf16 cols 8q..8q+7
      uint4 o = {0u, 0u, 0u, 0u};
      if (q < 21) {
        const float* xp = x + (size_t)r * 166 + 8 * q;
        unsigned int* ou = (unsigned int*)&o;
#pragma unroll
        for (int j = 0; j < 4; ++j) {
          int c = 8 * q + 2 * j;
          if (c + 1 < 166) {
            float2 v = *reinterpret_cast<const float2*>(xp + 2 * j);
            ou[j] = (unsigned)f2bf(v.x) | ((unsigned)f2bf(v.y) << 16);
          }
        }
      }
      reinterpret_cast<uint4*>(xbu)[(size_t)r * 24 + q] = o;
    } else {  // aggX pad uint4s: uints 80..95 (agg later overwrites 80..82)
      int j = q - 24;
      reinterpret_cast<uint4*>(aggX)[(size_t)r * 24 + 20 + j] = uint4{0u, 0u, 0u, 0u};
    }
    return;
  }
  b -= PREP_BLKS;
  if (b < PACK_BLKS) {
    int idx = b * 256 + threadIdx.x;
    if (idx < 98304) {  // w1c [256][384]
      int n = idx / 384, k = idx - n * 384;
      float v = 0.f;
      if (k < 166) v = Wl1[(size_t)n * 166 + k];
      else if (k >= 192 && k < 358) v = Wr1[(size_t)n * 166 + (k - 192)];
      w1c[idx] = f2bf(v);
    } else if (idx < 163840) {  // w2s [256][256]
      int j = idx - 98304;
      int n = j / 256, k = j - n * 256;
      w2s[j] = f2bf(n < 128 ? Wl2[(size_t)n * 256 + k] : Wr2[(size_t)(n - 128) * 256 + k]);
    } else if (idx < 180224) {  // w3s [128][128]
      int j = idx - 163840;
      int n = j / 128, k = j - n * 128;
      w3s[j] = f2bf(n < 64 ? Wle[(size_t)n * 128 + k] : Wre[(size_t)(n - 64) * 128 + k]);
    }
    return;
  }
  int z = (b - PACK_BLKS) * 256 + threadIdx.x;
  if (z < 1024) bnacc[z] = 0.f;
}

// ================= per-bucket scatter: begend + col =================
__global__ void k_bscatter(const uint2* __restrict__ pairs, const int* __restrict__ bcur,
                           int2* __restrict__ begend, int* __restrict__ col) {
  __shared__ int dcnt[NB], ts[NB], doff[NB], dcur[NB];
  int t = threadIdx.x;
  int b = blockIdx.x;
  int n0 = b * BNODES;
  int ncnt = min(NN - n0, BNODES);
  int e0 = b * CAP, e1 = e0 + bcur[b];
  dcnt[t] = 0;
  __syncthreads();
  for (int e = e0 + t; e < e1; e += 256) atomicAdd(&dcnt[pairs[e].y - n0], 1);
  __syncthreads();
  ts[t] = dcnt[t];
  __syncthreads();
#pragma unroll
  for (int off = 1; off < NB; off <<= 1) {
    int u = (t >= off) ? ts[t - off] : 0;
    __syncthreads();
    ts[t] += u;
    __syncthreads();
  }
  doff[t] = ts[t] - dcnt[t];
  dcur[t] = 0;
  if (t < ncnt) begend[n0 + t] = int2{e0 + doff[t], e0 + doff[t] + dcnt[t]};
  __syncthreads();
  for (int e = e0 + t; e < e1; e += 256) {
    uint2 pr = pairs[e];
    int ld = pr.y - n0;
    int p = atomicAdd(&dcur[ld], 1);
    col[e0 + doff[ld] + p] = (int)pr.x;
  }
}

// ================= bf16 mean aggregation (begend CSR) =================
template <int D, int U, bool FUSE, bool OUTBF, bool CLS>
__global__ __launch_bounds__(256) void k_aggb(
    const unsigned int* __restrict__ feat, int fsu,
    const int2* __restrict__ begend, const int* __restrict__ col,
    const unsigned int* __restrict__ self, int ssu,
    const float* __restrict__ bias,
    void* __restrict__ outv, int osu,
    const float* __restrict__ Wc, const float* __restrict__ bc,
    float* __restrict__ logits) {
  constexpr int D2 = D / 2;
  constexpr int LPN = (D2 < 64) ? D2 : 64;
  constexpr int NPB = 256 / LPN;
  constexpr int C = (D2 + LPN - 1) / LPN;
  int node = blockIdx.x * NPB + threadIdx.x / LPN;
  if (node >= NN) return;
  int lane = threadIdx.x % LPN;
  int2 be = begend[node];
  int beg = be.x, end = be.y;
  float ax[C], ay[C];
#pragma unroll
  for (int c = 0; c < C; ++c) { ax[c] = 0.f; ay[c] = 0.f; }

  int j = beg;
  for (; j + U <= end; j += U) {
    const unsigned int* fp[U];
#pragma unroll
    for (int u = 0; u < U; ++u) fp[u] = feat + (size_t)col[j + u] * fsu;
#pragma unroll
    for (int c = 0; c < C; ++c) {
      int p = lane + c * LPN;
      unsigned int t[U];
#pragma unroll
      for (int u = 0; u < U; ++u) t[u] = (p < D2) ? fp[u][p] : 0u;
#pragma unroll
      for (int u = 0; u < U; ++u) {
        ax[c] += bf2f(t[u] & 0xffffu);
        ay[c] += bf2f(t[u] >> 16);
      }
    }
  }
  for (; j < end; ++j) {
    const unsigned int* fr = feat + (size_t)col[j] * fsu;
#pragma unroll
    for (int c = 0; c < C; ++c) {
      int p = lane + c * LPN;
      if (p < D2) {
        unsigned int t = fr[p];
        ax[c] += bf2f(t & 0xffffu);
        ay[c] += bf2f(t >> 16);
      }
    }
  }
  float inv = 1.0f / fmaxf((float)(end - beg), 1.0f);
  float s0 = 0.f, s1 = 0.f;
#pragma unroll
  for (int c = 0; c < C; ++c) {
    int p = lane + c * LPN;
    if (p < D2) {
      float vx = ax[c] * inv, vy = ay[c] * inv;
      if constexpr (FUSE) {
        unsigned int s = self[(size_t)node * ssu + p];
        vx += bf2f(s & 0xffffu) + bias[2 * p];
        vy += bf2f(s >> 16) + bias[2 * p + 1];
      }
      if constexpr (OUTBF) {
        unsigned int o = (unsigned int)f2bf(vx) | ((unsigned int)f2bf(vy) << 16);
        ((unsigned int*)outv)[(size_t)node * osu + p] = o;
      } else {
        float2 o{vx, vy};
        *reinterpret_cast<float2*>((float*)outv + (size_t)node * osu + 2 * p) = o;
      }
      if constexpr (CLS) {
        s0 += vx * Wc[2 * p] + vy * Wc[2 * p + 1];
        s1 += vx * Wc[64 + 2 * p] + vy * Wc[64 + 2 * p + 1];
      }
    }
  }
  if constexpr (CLS) {
#pragma unroll
    for (int m = 1; m < LPN; m <<= 1) {
      s0 += __shfl_xor(s0, m);
      s1 += __shfl_xor(s1, m);
    }
    if (lane == 0) {
      logits[node * 2 + 0] = s0 + bc[0];
      logits[node * 2 + 1] = s1 + bc[1];
    }
  }
}

// ===== GEMM1: 128x128 tile, BK=32, 2x16KB dbuf (32KB LDS -> 4 blocks/CU), =====
// ===== counted vmcnt(4), A split at K1, bias + fused BN stats              =====
template <bool BIASED, bool STATS>
__global__ __launch_bounds__(256) void k_gemm_mfma(
    const unsigned short* __restrict__ A0, const unsigned short* __restrict__ A1,
    int K1, int Astride, int KC,
    const unsigned short* __restrict__ W,
    const float* __restrict__ bias,
    unsigned short* __restrict__ out, int Ntot,
    float* __restrict__ statacc) {
  __shared__ __align__(16) char lds[32768];
  int tid = threadIdx.x;
  int lane = tid & 63;
  int w = tid >> 6;
  int wr = w >> 1, wc = w & 1;
  int m0 = blockIdx.x * 128;
  int n0 = blockIdx.y * 128;

  // 64B rows: lane l -> row rbase+(l>>2), slot (l&3). Inverse-swizzled source col:
  int srow = lane >> 2;                                  // 0..15
  int ssw = (((lane & 3) ^ ((lane >> 2) & 3)) << 4);     // source byte col
  const char* Wb = (const char*)W;

  f32x4 acc[4][4];
#pragma unroll
  for (int i = 0; i < 4; ++i)
#pragma unroll
    for (int j = 0; j < 4; ++j) acc[i][j] = f32x4{0.f, 0.f, 0.f, 0.f};

  auto stage = [&](int buf, int kt) {  // 4 gl_lds per wave (2 A + 2 W)
    int k0 = kt << 5;
    const char* Ab = (const char*)(k0 < K1 ? A0 : A1);
    int koff = k0 < K1 ? k0 : k0 - K1;
    char* base = lds + buf * 16384;
#pragma unroll
    for (int i = 0; i < 2; ++i) {
      int row = w * 32 + i * 16 + srow;
      int ga = m0 + row;
      ga = ga < NN ? ga : NN - 1;  // clamp: garbage rows never stored
      gl_lds16((const char*)Ab + ((size_t)ga * Astride + koff) * 2 + ssw,
               base + w * 2048 + i * 1024);
      gl_lds16(Wb + ((size_t)(n0 + row) * KC + k0) * 2 + ssw,
               base + 8192 + w * 2048 + i * 1024);
    }
  };
  auto compute = [&](int buf) {
    char* lA = lds + buf * 16384;
    char* lB = lA + 8192;
    bf16x8 af[4], bfr[4];
    int ac = (lane >> 4) << 4;  // byte col 0,16,32,48
#pragma unroll
    for (int f = 0; f < 4; ++f) {
      int ar = wr * 64 + f * 16 + (lane & 15);
      af[f] = *reinterpret_cast<const bf16x8*>(lA + ar * 64 + (ac ^ ((ar & 3) << 4)));
      int br = wc * 64 + f * 16 + (lane & 15);
      bfr[f] = *reinterpret_cast<const bf16x8*>(lB + br * 64 + (ac ^ ((br & 3) << 4)));
    }
#pragma unroll
    for (int fm = 0; fm < 4; ++fm)
#pragma unroll
      for (int fn = 0; fn < 4; ++fn)
        acc[fm][fn] = __builtin_amdgcn_mfma_f32_16x16x32_bf16(af[fm], bfr[fn], acc[fm][fn], 0, 0, 0);
  };

  int nt = KC >> 5;            // 12 for GEMM1
  stage(0, 0);
  if (nt > 1) stage(1, 1);
  for (int t = 0; t < nt - 1; ++t) {
    asm volatile("s_waitcnt vmcnt(4)" ::: "memory");  // stage t landed; t+1 in flight
    __builtin_amdgcn_s_barrier();                     // raw barrier: no implicit drain
    compute(t & 1);
    __builtin_amdgcn_s_barrier();
    if (t + 2 < nt) stage(t & 1, t + 2);
  }
  asm volatile("s_waitcnt vmcnt(0)" ::: "memory");
  __builtin_amdgcn_s_barrier();
  compute((nt - 1) & 1);

  int nbase = n0 + wc * 64 + (lane & 15);
  float bv[4] = {0.f, 0.f, 0.f, 0.f};
  if constexpr (BIASED) {
#pragma unroll
    for (int fn = 0; fn < 4; ++fn) bv[fn] = bias[nbase + fn * 16];
  }
  float ssum[4] = {0.f, 0.f, 0.f, 0.f}, sqs[4] = {0.f, 0.f, 0.f, 0.f};
#pragma unroll
  for (int fm = 0; fm < 4; ++fm) {
    int mbase = m0 + wr * 64 + fm * 16 + ((lane >> 4) << 2);
#pragma unroll
    for (int j = 0; j < 4; ++j) {
      int m = mbase + j;
      if (m < NN) {
#pragma unroll
        for (int fn = 0; fn < 4; ++fn) {
          float v = acc[fm][fn][j] + bv[fn];
          out[(size_t)m * Ntot + nbase + fn * 16] = f2bf(v);
          if constexpr (STATS) { ssum[fn] += v; sqs[fn] += v * v; }
        }
      }
    }
  }
  if constexpr (STATS) {
#pragma unroll
    for (int fn = 0; fn < 4; ++fn) {
      float s = ssum[fn], q = sqs[fn];
      s += __shfl_xor(s, 16); s += __shfl_xor(s, 32);
      q += __shfl_xor(q, 16); q += __shfl_xor(q, 32);
      if (lane < 16) {
        atomicAdd(&statacc[nbase + fn * 16], s);
        atomicAdd(&statacc[Ntot + nbase + fn * 16], q);
      }
    }
  }
}

// ===== GEMM with fused BN+ReLU on A (layers 2,3): A reg-staged, W gl_lds, BK=64 =====
__global__ __launch_bounds__(256) void k_gemm_bn(
    const unsigned short* __restrict__ A, const float* __restrict__ scsh,
    const unsigned short* __restrict__ W,
    unsigned short* __restrict__ out, int KC, int Ntot) {
  __shared__ __align__(16) char lds[65536];
  int tid = threadIdx.x;
  int lane = tid & 63;
  int w = tid >> 6;
  int wr = w >> 1, wc = w & 1;
  int m0 = blockIdx.x * 128;
  int n0 = blockIdx.y * 128;

  int srow = lane >> 3;
  int cb = (lane & 7) << 4;
  int ssw = cb ^ (srow << 4);
  int kk0 = (lane & 7) << 3;
  const char* Wb = (const char*)W;

  f32x4 acc[4][4];
#pragma unroll
  for (int i = 0; i < 4; ++i)
#pragma unroll
    for (int j = 0; j < 4; ++j) acc[i][j] = f32x4{0.f, 0.f, 0.f, 0.f};

  uint4 areg[4];
  float4 sc[4];

  auto loadA = [&](int k0) {
    int kk = k0 + kk0;
    const float4* sp = (const float4*)(scsh + 2 * kk);
    sc[0] = sp[0]; sc[1] = sp[1]; sc[2] = sp[2]; sc[3] = sp[3];
#pragma unroll
    for (int i = 0; i < 4; ++i) {
      int row = w * 32 + i * 8 + srow;
      int ga = m0 + row;
      ga = ga < NN ? ga : NN - 1;
      areg[i] = *reinterpret_cast<const uint4*>(A + (size_t)ga * KC + kk);
    }
  };
  auto writeA = [&](int buf) {
    char* dstb = lds + buf * 32768;
#pragma unroll
    for (int i = 0; i < 4; ++i) {
      int row = w * 32 + i * 8 + srow;
      uint4 v = areg[i], o;
      float a, b;
      a = fmaxf(bf2f(v.x & 0xffffu) * sc[0].x + sc[0].y, 0.f);
      b = fmaxf(bf2f(v.x >> 16)     * sc[0].z + sc[0].w, 0.f);
      o.x = (unsigned)f2bf(a) | ((unsigned)f2bf(b) << 16);
      a = fmaxf(bf2f(v.y & 0xffffu) * sc[1].x + sc[1].y, 0.f);
      b = fmaxf(bf2f(v.y >> 16)     * sc[1].z + sc[1].w, 0.f);
      o.y = (unsigned)f2bf(a) | ((unsigned)f2bf(b) << 16);
      a = fmaxf(bf2f(v.z & 0xffffu) * sc[2].x + sc[2].y, 0.f);
      b = fmaxf(bf2f(v.z >> 16)     * sc[2].z + sc[2].w, 0.f);
      o.z = (unsigned)f2bf(a) | ((unsigned)f2bf(b) << 16);
      a = fmaxf(bf2f(v.w & 0xffffu) * sc[3].x + sc[3].y, 0.f);
      b = fmaxf(bf2f(v.w >> 16)     * sc[3].z + sc[3].w, 0.f);
      o.w = (unsigned)f2bf(a) | ((unsigned)f2bf(b) << 16);
      *reinterpret_cast<uint4*>(dstb + row * 128 + (cb ^ ((row & 7) << 4))) = o;
    }
  };
  auto stageW = [&](int buf, int k0) {
    char* dst = lds + buf * 32768 + 16384 + w * 4096;
#pragma unroll
    for (int i = 0; i < 4; ++i) {
      int row = w * 32 + i * 8 + srow;
      gl_lds16(Wb + ((size_t)(n0 + row) * KC + k0) * 2 + ssw, dst + i * 1024);
    }
  };
  auto compute = [&](int buf) {
    char* lA = lds + buf * 32768;
    char* lB = lA + 16384;
#pragma unroll
    for (int ks = 0; ks < 2; ++ks) {
      bf16x8 af[4], bfr[4];
      int ac = ks * 64 + ((lane >> 4) << 4);
#pragma unroll
      for (int f = 0; f < 4; ++f) {
        int ar = wr * 64 + f * 16 + (lane & 15);
        af[f] = *reinterpret_cast<const bf16x8*>(lA + ar * 128 + (ac ^ ((ar & 7) << 4)));
        int br = wc * 64 + f * 16 + (lane & 15);
        bfr[f] = *reinterpret_cast<const bf16x8*>(lB + br * 128 + (ac ^ ((br & 7) << 4)));
      }
#pragma unroll
      for (int fm = 0; fm < 4; ++fm)
#pragma unroll
        for (int fn = 0; fn < 4; ++fn)
          acc[fm][fn] = __builtin_amdgcn_mfma_f32_16x16x32_bf16(af[fm], bfr[fn], acc[fm][fn], 0, 0, 0);
    }
  };

  int nt = KC >> 6;  // 4 / 2
  loadA(0);
  stageW(0, 0);
  writeA(0);
  __syncthreads();
  int cur = 0;
  for (int t = 0; t < nt; ++t) {
    if (t + 1 < nt) { loadA((t + 1) << 6); stageW(cur ^ 1, (t + 1) << 6); }
    compute(cur);
    __syncthreads();
    if (t + 1 < nt) writeA(cur ^ 1);
    __syncthreads();
    cur ^= 1;
  }

  int nbase = n0 + wc * 64 + (lane & 15);
#pragma unroll
  for (int fm = 0; fm < 4; ++fm) {
    int mbase = m0 + wr * 64 + fm * 16 + ((lane >> 4) << 2);
#pragma unroll
    for (int j = 0; j < 4; ++j) {
      int m = mbase + j;
      if (m < NN) {
#pragma unroll
        for (int fn = 0; fn < 4; ++fn)
          out[(size_t)m * Ntot + nbase + fn * 16] = f2bf(acc[fm][fn][j]);
      }
    }
  }
}

// ================= BN: stats + scale/shift precompute =================
template <int N, bool BF>
__global__ __launch_bounds__(256) void k_bn_stats2(const void* __restrict__ hv,
                                                   float* __restrict__ acc) {
  constexpr int CP = N / 2;
  constexpr int RG = 256 / CP;
  int cp = threadIdx.x % CP, rg = threadIdx.x / CP;
  int rpb = (NN + gridDim.x - 1) / gridDim.x;
  int r0 = blockIdx.x * rpb, r1 = min(r0 + rpb, NN);
  float s0 = 0.f, s1 = 0.f, q0 = 0.f, q1 = 0.f;
  for (int r = r0 + rg; r < r1; r += RG) {
    float v0, v1;
    if constexpr (BF) {
      unsigned int u = ((const unsigned int*)hv)[(size_t)r * CP + cp];
      v0 = bf2f(u & 0xffffu); v1 = bf2f(u >> 16);
    } else {
      float2 u = ((const float2*)hv)[(size_t)r * CP + cp];
      v0 = u.x; v1 = u.y;
    }
    s0 += v0; s1 += v1; q0 += v0 * v0; q1 += v1 * v1;
  }
  __shared__ float l0[256], l1[256], l2[256], l3[256];
  l0[threadIdx.x] = s0; l1[threadIdx.x] = s1; l2[threadIdx.x] = q0; l3[threadIdx.x] = q1;
  __syncthreads();
  if (rg == 0) {
#pragma unroll
    for (int g = 1; g < RG; ++g) {
      s0 += l0[g * CP + cp]; s1 += l1[g * CP + cp];
      q0 += l2[g * CP + cp]; q1 += l3[g * CP + cp];
    }
    atomicAdd(&acc[2 * cp], s0);
    atomicAdd(&acc[2 * cp + 1], s1);
    atomicAdd(&acc[N + 2 * cp], q0);
    atomicAdd(&acc[N + 2 * cp + 1], q1);
  }
}

template <int N>
__global__ void k_scsh(const float* __restrict__ acc, const float* __restrict__ g,
                       const float* __restrict__ b, float* __restrict__ scsh) {
  int c = threadIdx.x;  // blockDim == N
  float mean = acc[c] * (1.0f / NN);
  float var = acc[N + c] * (1.0f / NN) - mean * mean;
  float sc = g[c] * rsqrtf(var + BN_EPS);
  scsh[2 * c] = sc;
  scsh[2 * c + 1] = b[c] - mean * sc;
}

extern "C" void kernel_launch(void* const* d_in, const int* in_sizes, int n_in,
                              void* d_out, int out_size, void* d_ws, size_t ws_size,
                              hipStream_t stream) {
  const float* x   = (const float*)d_in[0];
  const int* ei    = (const int*)d_in[1];
  const float* Wl1 = (const float*)d_in[2];
  const float* Wr1 = (const float*)d_in[3];
  const float* b1  = (const float*)d_in[4];
  const float* Wl2 = (const float*)d_in[5];
  const float* Wr2 = (const float*)d_in[6];
  const float* b2  = (const float*)d_in[7];
  const float* Wle = (const float*)d_in[8];
  const float* Wre = (const float*)d_in[9];
  const float* be  = (const float*)d_in[10];
  const float* g1  = (const float*)d_in[11];
  const float* bt1 = (const float*)d_in[12];
  const float* g2  = (const float*)d_in[13];
  const float* bt2 = (const float*)d_in[14];
  const float* Wc  = (const float*)d_in[15];
  const float* bc  = (const float*)d_in[16];

  const int* src = ei;
  const int* dst = ei + NE;

  char* ws = (char*)d_ws;
  size_t off = 0;
  auto take = [&](size_t bytes) -> char* {
    char* p = ws + off;
    off = (off + bytes + 255) & ~(size_t)255;
    return p;
  };
  int* bkt_cur   = (int*)take(1024);
  float* bnacc1  = (float*)take(2048);   // zeroed by k_front tail blocks
  float* bnacc2  = (float*)take(2048);
  float* scsh1   = (float*)take(512 * 4);
  float* scsh2   = (float*)take(256 * 4);
  int2* begend   = (int2*)take((size_t)NN * 8);
  uint2* pairs   = (uint2*)take((size_t)NB * CAP * 8);
  int* col       = (int*)take((size_t)NB * CAP * 4);
  unsigned short* w1c = (unsigned short*)take((size_t)256 * 384 * 2);
  unsigned short* w2s = (unsigned short*)take((size_t)256 * 256 * 2);
  unsigned short* w3s = (unsigned short*)take((size_t)128 * 128 * 2);
  unsigned int* xbu  = (unsigned int*)take((size_t)NN * 96 * 4);
  unsigned int* aggX = (unsigned int*)take((size_t)NN * 96 * 4);
  char* P1 = take((size_t)NN * 256 * 2);
  char* P0 = take((size_t)NN * 256 * 2);

  unsigned short* h1raw = (unsigned short*)P1;  // [NN][256] bf16
  unsigned short* z2    = (unsigned short*)P0;  // [NN][256] bf16
  unsigned short* h2raw = (unsigned short*)P1;  // [NN][128] bf16
  unsigned short* z3    = (unsigned short*)P0;  // [NN][128] bf16

  float* logits = (float*)d_out;
  float* emb    = (float*)d_out + (size_t)NN * 2;

  hipMemsetAsync(bkt_cur, 0, 1024, stream);

  // fused front: bpart + prep_x + pack_w + bnacc zero
  {
    int grid = BPART_BLKS + PREP_BLKS + PACK_BLKS + 4;
    k_front<<<grid, 256, 0, stream>>>(src, dst, bkt_cur, pairs, x, xbu, aggX,
                                      Wl1, Wr1, Wl2, Wr2, Wle, Wre, w1c, w2s, w3s, bnacc1);
  }
  k_bscatter<<<NB, NB, 0, stream>>>(pairs, bkt_cur, begend, col);

  // ---- layer 1: aggX = agg(xbu); h1raw = [aggX | xbu] @ w1c + b1 (+BN stats) ----
  k_aggb<166, 8, false, true, false><<<(NN + 3) / 4, 256, 0, stream>>>(
      xbu, 96, begend, col, nullptr, 0, nullptr, aggX, 96, nullptr, nullptr, nullptr);
  {
    dim3 g((NN + 127) / 128, 2);
    k_gemm_mfma<true, true><<<g, 256, 0, stream>>>(
        (const unsigned short*)aggX, (const unsigned short*)xbu, 192, 192, 384,
        w1c, b1, h1raw, 256, bnacc1);
  }
  k_scsh<256><<<1, 256, 0, stream>>>(bnacc1, g1, bt1, scsh1);

  // ---- layer 2: z2 = BN1(h1raw) @ [Wl2;Wr2]^T (BN fused in A-staging);
  //      h2raw = agg(z2[:,:128]) + z2[:,128:] + b2 (bf16 out) ----
  {
    dim3 g((NN + 127) / 128, 2);
    k_gemm_bn<<<g, 256, 0, stream>>>(h1raw, scsh1, w2s, z2, 256, 256);
  }
  k_aggb<128, 8, true, true, false><<<(NN + 3) / 4, 256, 0, stream>>>(
      (const unsigned int*)z2, 128, begend, col, (const unsigned int*)z2 + 64, 128, b2,
      h2raw, 64, nullptr, nullptr, nullptr);
  k_bn_stats2<128, true><<<512, 256, 0, stream>>>(h2raw, bnacc2);
  k_scsh<128><<<1, 128, 0, stream>>>(bnacc2, g2, bt2, scsh2);

  // ---- layer 3: z3 = BN2(h2raw) @ [Wle;Wre]^T; emb = agg(z3[:,:64]) + z3[:,64:] + be ----
  {
    dim3 g((NN + 127) / 128, 1);
    k_gemm_bn<<<g, 256, 0, stream>>>(h2raw, scsh2, w3s, z3, 128, 128);
  }
  k_aggb<64, 8, true, false, true><<<(NN + 7) / 8, 256, 0, stream>>>(
      (const unsigned int*)z3, 64, begend, col, (const unsigned int*)z3 + 32, 64, be,
      emb, 64, Wc, bc, logits);
}

// Round 19
// 273.721 us; speedup vs baseline: 1.0317x; 1.0317x over previous
//
#include <hip/hip_runtime.h>

#define NN 50000
#define NE 800000
#define NB 256
#define BNODES ((NN + NB - 1) / NB)  // 196 nodes per bucket
#define CAP 4096                     // bucket window capacity (mean 3125, +17 sigma)
#define BPART_BLKS ((NE + 8191) / 8192)          // 98
#define PREP_BLKS ((NN * 112 + 255) / 256)       // 21875
#define PACK_BLKS ((180224 + 255) / 256)         // 704
static constexpr float BN_EPS = 1e-5f;

typedef __attribute__((ext_vector_type(8))) short bf16x8;
typedef __attribute__((ext_vector_type(4))) float f32x4;

__device__ inline unsigned short f2bf(float f) {
  unsigned int u = __float_as_uint(f);
  return (unsigned short)((u + 0x7FFFu + ((u >> 16) & 1u)) >> 16);
}
__device__ inline float bf2f(unsigned int h) { return __uint_as_float(h << 16); }
__device__ inline void gl_lds16(const char* g, char* l) {
  __builtin_amdgcn_global_load_lds((const __attribute__((address_space(1))) void*)g,
                                   (__attribute__((address_space(3))) void*)l, 16, 0, 0);
}

// ========== fused front kernel: bpart | prep_x | pack_w | bnacc zero ==========
__device__ void dev_bpart(int bb, const int* __restrict__ src, const int* __restrict__ dst,
                          int* __restrict__ bcur, uint2* __restrict__ pairs) {
  __shared__ int cnt[NB], lbase[NB], lcur[NB];
  int t = threadIdx.x;
  cnt[t] = 0;
  __syncthreads();
  int e0 = bb * 8192 + t;
#pragma unroll
  for (int i = 0; i < 32; ++i) {
    int e = e0 + i * 256;
    if (e < NE) atomicAdd(&cnt[dst[e] / BNODES], 1);
  }
  __syncthreads();
  lbase[t] = cnt[t] ? (t * CAP + atomicAdd(&bcur[t], cnt[t])) : 0;
  lcur[t] = 0;
  __syncthreads();
#pragma unroll
  for (int i = 0; i < 32; ++i) {
    int e = e0 + i * 256;
    if (e < NE) {
      int d = dst[e];
      int b = d / BNODES;
      int p = atomicAdd(&lcur[b], 1);
      pairs[(size_t)lbase[b] + p] = uint2{(unsigned)src[e], (unsigned)d};
    }
  }
}

__global__ void k_front(const int* __restrict__ src, const int* __restrict__ dst,
                        int* __restrict__ bcur, uint2* __restrict__ pairs,
                        const float* __restrict__ x, unsigned int* __restrict__ xbu,
                        unsigned int* __restrict__ aggX,
                        const float* __restrict__ Wl1, const float* __restrict__ Wr1,
                        const float* __restrict__ Wl2, const float* __restrict__ Wr2,
                        const float* __restrict__ Wle, const float* __restrict__ Wre,
                        unsigned short* __restrict__ w1c, unsigned short* __restrict__ w2s,
                        unsigned short* __restrict__ w3s,
                        float* __restrict__ bnacc) {
  int b = blockIdx.x;
  if (b < BPART_BLKS) {
    dev_bpart(b, src, dst, bcur, pairs);
    return;
  }
  b -= BPART_BLKS;
  if (b < PREP_BLKS) {
    int i = b * 256 + threadIdx.x;
    if (i >= NN * 112) return;
    int r = i / 112, q = i - r * 112;
    if (q < 84) {
      int c0 = 2 * q, c1 = c0 + 1;
      float v0 = (c0 < 166) ? x[(size_t)r * 166 + c0] : 0.f;
      float v1 = (c1 < 166) ? x[(size_t)r * 166 + c1] : 0.f;
      xbu[(size_t)r * 96 + q] = (unsigned)f2bf(v0) | ((unsigned)f2bf(v1) << 16);
    } else if (q < 96) {
      xbu[(size_t)r * 96 + q] = 0u;          // x pads
    } else if (q < 109) {
      aggX[(size_t)r * 96 + 83 + (q - 96)] = 0u;  // agg pads (uints 83..95)
    }
    return;
  }
  b -= PREP_BLKS;
  if (b < PACK_BLKS) {
    int idx = b * 256 + threadIdx.x;
    if (idx < 98304) {  // w1c [256][384]
      int n = idx / 384, k = idx - n * 384;
      float v = 0.f;
      if (k < 166) v = Wl1[(size_t)n * 166 + k];
      else if (k >= 192 && k < 358) v = Wr1[(size_t)n * 166 + (k - 192)];
      w1c[idx] = f2bf(v);
    } else if (idx < 163840) {  // w2s [256][256]
      int j = idx - 98304;
      int n = j / 256, k = j - n * 256;
      w2s[j] = f2bf(n < 128 ? Wl2[(size_t)n * 256 + k] : Wr2[(size_t)(n - 128) * 256 + k]);
    } else if (idx < 180224) {  // w3s [128][128]
      int j = idx - 163840;
      int n = j / 128, k = j - n * 128;
      w3s[j] = f2bf(n < 64 ? Wle[(size_t)n * 128 + k] : Wre[(size_t)(n - 64) * 128 + k]);
    }
    return;
  }
  int z = (b - PACK_BLKS) * 256 + threadIdx.x;
  if (z < 1024) bnacc[z] = 0.f;
}

// ================= per-bucket scatter: begend + col =================
__global__ void k_bscatter(const uint2* __restrict__ pairs, const int* __restrict__ bcur,
                           int2* __restrict__ begend, int* __restrict__ col) {
  __shared__ int dcnt[NB], ts[NB], doff[NB], dcur[NB];
  int t = threadIdx.x;
  int b = blockIdx.x;
  int n0 = b * BNODES;
  int ncnt = min(NN - n0, BNODES);
  int e0 = b * CAP, e1 = e0 + bcur[b];
  dcnt[t] = 0;
  __syncthreads();
  for (int e = e0 + t; e < e1; e += 256) atomicAdd(&dcnt[pairs[e].y - n0], 1);
  __syncthreads();
  ts[t] = dcnt[t];
  __syncthreads();
#pragma unroll
  for (int off = 1; off < NB; off <<= 1) {
    int u = (t >= off) ? ts[t - off] : 0;
    __syncthreads();
    ts[t] += u;
    __syncthreads();
  }
  doff[t] = ts[t] - dcnt[t];
  dcur[t] = 0;
  if (t < ncnt) begend[n0 + t] = int2{e0 + doff[t], e0 + doff[t] + dcnt[t]};
  __syncthreads();
  for (int e = e0 + t; e < e1; e += 256) {
    uint2 pr = pairs[e];
    int ld = pr.y - n0;
    int p = atomicAdd(&dcur[ld], 1);
    col[e0 + doff[ld] + p] = (int)pr.x;
  }
}

// ================= bf16 mean aggregation (begend CSR) =================
template <int D, int U, bool FUSE, bool OUTBF, bool CLS>
__global__ __launch_bounds__(256) void k_aggb(
    const unsigned int* __restrict__ feat, int fsu,
    const int2* __restrict__ begend, const int* __restrict__ col,
    const unsigned int* __restrict__ self, int ssu,
    const float* __restrict__ bias,
    void* __restrict__ outv, int osu,
    const float* __restrict__ Wc, const float* __restrict__ bc,
    float* __restrict__ logits) {
  constexpr int D2 = D / 2;
  constexpr int LPN = (D2 < 64) ? D2 : 64;
  constexpr int NPB = 256 / LPN;
  constexpr int C = (D2 + LPN - 1) / LPN;
  int node = blockIdx.x * NPB + threadIdx.x / LPN;
  if (node >= NN) return;
  int lane = threadIdx.x % LPN;
  int2 be = begend[node];
  int beg = be.x, end = be.y;
  float ax[C], ay[C];
#pragma unroll
  for (int c = 0; c < C; ++c) { ax[c] = 0.f; ay[c] = 0.f; }

  int j = beg;
  for (; j + U <= end; j += U) {
    const unsigned int* fp[U];
#pragma unroll
    for (int u = 0; u < U; ++u) fp[u] = feat + (size_t)col[j + u] * fsu;
#pragma unroll
    for (int c = 0; c < C; ++c) {
      int p = lane + c * LPN;
      unsigned int t[U];
#pragma unroll
      for (int u = 0; u < U; ++u) t[u] = (p < D2) ? fp[u][p] : 0u;
#pragma unroll
      for (int u = 0; u < U; ++u) {
        ax[c] += bf2f(t[u] & 0xffffu);
        ay[c] += bf2f(t[u] >> 16);
      }
    }
  }
  for (; j < end; ++j) {
    const unsigned int* fr = feat + (size_t)col[j] * fsu;
#pragma unroll
    for (int c = 0; c < C; ++c) {
      int p = lane + c * LPN;
      if (p < D2) {
        unsigned int t = fr[p];
        ax[c] += bf2f(t & 0xffffu);
        ay[c] += bf2f(t >> 16);
      }
    }
  }
  float inv = 1.0f / fmaxf((float)(end - beg), 1.0f);
  float s0 = 0.f, s1 = 0.f;
#pragma unroll
  for (int c = 0; c < C; ++c) {
    int p = lane + c * LPN;
    if (p < D2) {
      float vx = ax[c] * inv, vy = ay[c] * inv;
      if constexpr (FUSE) {
        unsigned int s = self[(size_t)node * ssu + p];
        vx += bf2f(s & 0xffffu) + bias[2 * p];
        vy += bf2f(s >> 16) + bias[2 * p + 1];
      }
      if constexpr (OUTBF) {
        unsigned int o = (unsigned int)f2bf(vx) | ((unsigned int)f2bf(vy) << 16);
        ((unsigned int*)outv)[(size_t)node * osu + p] = o;
      } else {
        float2 o{vx, vy};
        *reinterpret_cast<float2*>((float*)outv + (size_t)node * osu + 2 * p) = o;
      }
      if constexpr (CLS) {
        s0 += vx * Wc[2 * p] + vy * Wc[2 * p + 1];
        s1 += vx * Wc[64 + 2 * p] + vy * Wc[64 + 2 * p + 1];
      }
    }
  }
  if constexpr (CLS) {
#pragma unroll
    for (int m = 1; m < LPN; m <<= 1) {
      s0 += __shfl_xor(s0, m);
      s1 += __shfl_xor(s1, m);
    }
    if (lane == 0) {
      logits[node * 2 + 0] = s0 + bc[0];
      logits[node * 2 + 1] = s1 + bc[1];
    }
  }
}

// ===== GEMM1 (counted-vmcnt): 128x128, BK=64, 2x32KB dbuf, A split at K1, bias+stats =====
template <bool BIASED, bool STATS>
__global__ __launch_bounds__(256) void k_gemm_mfma(
    const unsigned short* __restrict__ A0, const unsigned short* __restrict__ A1,
    int K1, int Astride, int KC,
    const unsigned short* __restrict__ W,
    const float* __restrict__ bias,
    unsigned short* __restrict__ out, int Ntot,
    float* __restrict__ statacc) {
  __shared__ __align__(16) char lds[65536];
  int tid = threadIdx.x;
  int lane = tid & 63;
  int w = tid >> 6;
  int wr = w >> 1, wc = w & 1;
  int m0 = blockIdx.x * 128;
  int n0 = blockIdx.y * 128;

  int srow = lane >> 3;
  int scol = (lane & 7) << 4;
  int ssw = scol ^ (srow << 4);
  const char* Wb = (const char*)W;

  f32x4 acc[4][4];
#pragma unroll
  for (int i = 0; i < 4; ++i)
#pragma unroll
    for (int j = 0; j < 4; ++j) acc[i][j] = f32x4{0.f, 0.f, 0.f, 0.f};

  auto stage = [&](int buf, int k0) {
    const char* Ab = (const char*)(k0 < K1 ? A0 : A1);
    int koff = k0 < K1 ? k0 : k0 - K1;
    char* dst = lds + buf * 32768 + w * 4096;
#pragma unroll
    for (int i = 0; i < 4; ++i) {
      int row = w * 32 + i * 8 + srow;
      int ga = m0 + row;
      ga = ga < NN ? ga : NN - 1;
      gl_lds16(Ab + ((size_t)ga * Astride + koff) * 2 + ssw, dst + i * 1024);
      gl_lds16(Wb + ((size_t)(n0 + row) * KC + k0) * 2 + ssw, dst + 16384 + i * 1024);
    }
  };
  auto compute = [&](int buf) {
    char* lA = lds + buf * 32768;
    char* lB = lA + 16384;
#pragma unroll
    for (int ks = 0; ks < 2; ++ks) {
      bf16x8 af[4], bfr[4];
      int ac = ks * 64 + ((lane >> 4) << 4);
#pragma unroll
      for (int f = 0; f < 4; ++f) {
        int ar = wr * 64 + f * 16 + (lane & 15);
        af[f] = *reinterpret_cast<const bf16x8*>(lA + ar * 128 + (ac ^ ((ar & 7) << 4)));
        int br = wc * 64 + f * 16 + (lane & 15);
        bfr[f] = *reinterpret_cast<const bf16x8*>(lB + br * 128 + (ac ^ ((br & 7) << 4)));
      }
#pragma unroll
      for (int fm = 0; fm < 4; ++fm)
#pragma unroll
        for (int fn = 0; fn < 4; ++fn)
          acc[fm][fn] = __builtin_amdgcn_mfma_f32_16x16x32_bf16(af[fm], bfr[fn], acc[fm][fn], 0, 0, 0);
    }
  };

  int nt = KC >> 6;
  stage(0, 0);
  if (nt > 1) stage(1, 64);
  for (int t = 0; t < nt - 1; ++t) {
    asm volatile("s_waitcnt vmcnt(8)" ::: "memory");
    __builtin_amdgcn_s_barrier();
    compute(t & 1);
    __builtin_amdgcn_s_barrier();
    if (t + 2 < nt) stage(t & 1, (t + 2) << 6);
  }
  asm volatile("s_waitcnt vmcnt(0)" ::: "memory");
  __builtin_amdgcn_s_barrier();
  compute((nt - 1) & 1);

  int nbase = n0 + wc * 64 + (lane & 15);
  float bv[4] = {0.f, 0.f, 0.f, 0.f};
  if constexpr (BIASED) {
#pragma unroll
    for (int fn = 0; fn < 4; ++fn) bv[fn] = bias[nbase + fn * 16];
  }
  float ssum[4] = {0.f, 0.f, 0.f, 0.f}, sqs[4] = {0.f, 0.f, 0.f, 0.f};
#pragma unroll
  for (int fm = 0; fm < 4; ++fm) {
    int mbase = m0 + wr * 64 + fm * 16 + ((lane >> 4) << 2);
#pragma unroll
    for (int j = 0; j < 4; ++j) {
      int m = mbase + j;
      if (m < NN) {
#pragma unroll
        for (int fn = 0; fn < 4; ++fn) {
          float v = acc[fm][fn][j] + bv[fn];
          out[(size_t)m * Ntot + nbase + fn * 16] = f2bf(v);
          if constexpr (STATS) { ssum[fn] += v; sqs[fn] += v * v; }
        }
      }
    }
  }
  if constexpr (STATS) {
#pragma unroll
    for (int fn = 0; fn < 4; ++fn) {
      float s = ssum[fn], q = sqs[fn];
      s += __shfl_xor(s, 16); s += __shfl_xor(s, 32);
      q += __shfl_xor(q, 16); q += __shfl_xor(q, 32);
      if (lane < 16) {
        atomicAdd(&statacc[nbase + fn * 16], s);
        atomicAdd(&statacc[Ntot + nbase + fn * 16], q);
      }
    }
  }
}

// ===== GEMM with fused BN+ReLU on A (layers 2,3): A reg-staged + transformed, W gl_lds =====
__global__ __launch_bounds__(256) void k_gemm_bn(
    const unsigned short* __restrict__ A, const float* __restrict__ scsh,
    const unsigned short* __restrict__ W,
    unsigned short* __restrict__ out, int KC, int Ntot) {
  __shared__ __align__(16) char lds[65536];
  int tid = threadIdx.x;
  int lane = tid & 63;
  int w = tid >> 6;
  int wr = w >> 1, wc = w & 1;
  int m0 = blockIdx.x * 128;
  int n0 = blockIdx.y * 128;

  int srow = lane >> 3;
  int cb = (lane & 7) << 4;
  int ssw = cb ^ (srow << 4);
  int kk0 = (lane & 7) << 3;
  const char* Wb = (const char*)W;

  f32x4 acc[4][4];
#pragma unroll
  for (int i = 0; i < 4; ++i)
#pragma unroll
    for (int j = 0; j < 4; ++j) acc[i][j] = f32x4{0.f, 0.f, 0.f, 0.f};

  uint4 areg[4];
  float4 sc[4];

  auto loadA = [&](int k0) {
    int kk = k0 + kk0;
    const float4* sp = (const float4*)(scsh + 2 * kk);
    sc[0] = sp[0]; sc[1] = sp[1]; sc[2] = sp[2]; sc[3] = sp[3];
#pragma unroll
    for (int i = 0; i < 4; ++i) {
      int row = w * 32 + i * 8 + srow;
      int ga = m0 + row;
      ga = ga < NN ? ga : NN - 1;
      areg[i] = *reinterpret_cast<const uint4*>(A + (size_t)ga * KC + kk);
    }
  };
  auto writeA = [&](int buf) {
    char* dstb = lds + buf * 32768;
#pragma unroll
    for (int i = 0; i < 4; ++i) {
      int row = w * 32 + i * 8 + srow;
      uint4 v = areg[i], o;
      float a, b;
      a = fmaxf(bf2f(v.x & 0xffffu) * sc[0].x + sc[0].y, 0.f);
      b = fmaxf(bf2f(v.x >> 16)     * sc[0].z + sc[0].w, 0.f);
      o.x = (unsigned)f2bf(a) | ((unsigned)f2bf(b) << 16);
      a = fmaxf(bf2f(v.y & 0xffffu) * sc[1].x + sc[1].y, 0.f);
      b = fmaxf(bf2f(v.y >> 16)     * sc[1].z + sc[1].w, 0.f);
      o.y = (unsigned)f2bf(a) | ((unsigned)f2bf(b) << 16);
      a = fmaxf(bf2f(v.z & 0xffffu) * sc[2].x + sc[2].y, 0.f);
      b = fmaxf(bf2f(v.z >> 16)     * sc[2].z + sc[2].w, 0.f);
      o.z = (unsigned)f2bf(a) | ((unsigned)f2bf(b) << 16);
      a = fmaxf(bf2f(v.w & 0xffffu) * sc[3].x + sc[3].y, 0.f);
      b = fmaxf(bf2f(v.w >> 16)     * sc[3].z + sc[3].w, 0.f);
      o.w = (unsigned)f2bf(a) | ((unsigned)f2bf(b) << 16);
      *reinterpret_cast<uint4*>(dstb + row * 128 + (cb ^ ((row & 7) << 4))) = o;
    }
  };
  auto stageW = [&](int buf, int k0) {
    char* dst = lds + buf * 32768 + 16384 + w * 4096;
#pragma unroll
    for (int i = 0; i < 4; ++i) {
      int row = w * 32 + i * 8 + srow;
      gl_lds16(Wb + ((size_t)(n0 + row) * KC + k0) * 2 + ssw, dst + i * 1024);
    }
  };
  auto compute = [&](int buf) {
    char* lA = lds + buf * 32768;
    char* lB = lA + 16384;
#pragma unroll
    for (int ks = 0; ks < 2; ++ks) {
      bf16x8 af[4], bfr[4];
      int ac = ks * 64 + ((lane >> 4) << 4);
#pragma unroll
      for (int f = 0; f < 4; ++f) {
        int ar = wr * 64 + f * 16 + (lane & 15);
        af[f] = *reinterpret_cast<const bf16x8*>(lA + ar * 128 + (ac ^ ((ar & 7) << 4)));
        int br = wc * 64 + f * 16 + (lane & 15);
        bfr[f] = *reinterpret_cast<const bf16x8*>(lB + br * 128 + (ac ^ ((br & 7) << 4)));
      }
#pragma unroll
      for (int fm = 0; fm < 4; ++fm)
#pragma unroll
        for (int fn = 0; fn < 4; ++fn)
          acc[fm][fn] = __builtin_amdgcn_mfma_f32_16x16x32_bf16(af[fm], bfr[fn], acc[fm][fn], 0, 0, 0);
    }
  };

  int nt = KC >> 6;  // 4 / 2
  loadA(0);
  stageW(0, 0);
  writeA(0);
  __syncthreads();
  int cur = 0;
  for (int t = 0; t < nt; ++t) {
    if (t + 1 < nt) { loadA((t + 1) << 6); stageW(cur ^ 1, (t + 1) << 6); }
    compute(cur);
    __syncthreads();
    if (t + 1 < nt) writeA(cur ^ 1);
    __syncthreads();
    cur ^= 1;
  }

  int nbase = n0 + wc * 64 + (lane & 15);
#pragma unroll
  for (int fm = 0; fm < 4; ++fm) {
    int mbase = m0 + wr * 64 + fm * 16 + ((lane >> 4) << 2);
#pragma unroll
    for (int j = 0; j < 4; ++j) {
      int m = mbase + j;
      if (m < NN) {
#pragma unroll
        for (int fn = 0; fn < 4; ++fn)
          out[(size_t)m * Ntot + nbase + fn * 16] = f2bf(acc[fm][fn][j]);
      }
    }
  }
}

// ================= BN: stats + scale/shift precompute =================
template <int N, bool BF>
__global__ __launch_bounds__(256) void k_bn_stats2(const void* __restrict__ hv,
                                                   float* __restrict__ acc) {
  constexpr int CP = N / 2;
  constexpr int RG = 256 / CP;
  int cp = threadIdx.x % CP, rg = threadIdx.x / CP;
  int rpb = (NN + gridDim.x - 1) / gridDim.x;
  int r0 = blockIdx.x * rpb, r1 = min(r0 + rpb, NN);
  float s0 = 0.f, s1 = 0.f, q0 = 0.f, q1 = 0.f;
  for (int r = r0 + rg; r < r1; r += RG) {
    float v0, v1;
    if constexpr (BF) {
      unsigned int u = ((const unsigned int*)hv)[(size_t)r * CP + cp];
      v0 = bf2f(u & 0xffffu); v1 = bf2f(u >> 16);
    } else {
      float2 u = ((const float2*)hv)[(size_t)r * CP + cp];
      v0 = u.x; v1 = u.y;
    }
    s0 += v0; s1 += v1; q0 += v0 * v0; q1 += v1 * v1;
  }
  __shared__ float l0[256], l1[256], l2[256], l3[256];
  l0[threadIdx.x] = s0; l1[threadIdx.x] = s1; l2[threadIdx.x] = q0; l3[threadIdx.x] = q1;
  __syncthreads();
  if (rg == 0) {
#pragma unroll
    for (int g = 1; g < RG; ++g) {
      s0 += l0[g * CP + cp]; s1 += l1[g * CP + cp];
      q0 += l2[g * CP + cp]; q1 += l3[g * CP + cp];
    }
    atomicAdd(&acc[2 * cp], s0);
    atomicAdd(&acc[2 * cp + 1], s1);
    atomicAdd(&acc[N + 2 * cp], q0);
    atomicAdd(&acc[N + 2 * cp + 1], q1);
  }
}

template <int N>
__global__ void k_scsh(const float* __restrict__ acc, const float* __restrict__ g,
                       const float* __restrict__ b, float* __restrict__ scsh) {
  int c = threadIdx.x;  // blockDim == N
  float mean = acc[c] * (1.0f / NN);
  float var = acc[N + c] * (1.0f / NN) - mean * mean;
  float sc = g[c] * rsqrtf(var + BN_EPS);
  scsh[2 * c] = sc;
  scsh[2 * c + 1] = b[c] - mean * sc;
}

extern "C" void kernel_launch(void* const* d_in, const int* in_sizes, int n_in,
                              void* d_out, int out_size, void* d_ws, size_t ws_size,
                              hipStream_t stream) {
  const float* x   = (const float*)d_in[0];
  const int* ei    = (const int*)d_in[1];
  const float* Wl1 = (const float*)d_in[2];
  const float* Wr1 = (const float*)d_in[3];
  const float* b1  = (const float*)d_in[4];
  const float* Wl2 = (const float*)d_in[5];
  const float* Wr2 = (const float*)d_in[6];
  const float* b2  = (const float*)d_in[7];
  const float* Wle = (const float*)d_in[8];
  const float* Wre = (const float*)d_in[9];
  const float* be  = (const float*)d_in[10];
  const float* g1  = (const float*)d_in[11];
  const float* bt1 = (const float*)d_in[12];
  const float* g2  = (const float*)d_in[13];
  const float* bt2 = (const float*)d_in[14];
  const float* Wc  = (const float*)d_in[15];
  const float* bc  = (const float*)d_in[16];

  const int* src = ei;
  const int* dst = ei + NE;

  char* ws = (char*)d_ws;
  size_t off = 0;
  auto take = [&](size_t bytes) -> char* {
    char* p = ws + off;
    off = (off + bytes + 255) & ~(size_t)255;
    return p;
  };
  int* bkt_cur   = (int*)take(1024);
  float* bnacc1  = (float*)take(2048);   // zeroed by k_front tail blocks
  float* bnacc2  = (float*)take(2048);
  float* scsh1   = (float*)take(512 * 4);
  float* scsh2   = (float*)take(256 * 4);
  int2* begend   = (int2*)take((size_t)NN * 8);
  uint2* pairs   = (uint2*)take((size_t)NB * CAP * 8);
  int* col       = (int*)take((size_t)NB * CAP * 4);
  unsigned short* w1c = (unsigned short*)take((size_t)256 * 384 * 2);
  unsigned short* w2s = (unsigned short*)take((size_t)256 * 256 * 2);
  unsigned short* w3s = (unsigned short*)take((size_t)128 * 128 * 2);
  unsigned int* xbu  = (unsigned int*)take((size_t)NN * 96 * 4);
  unsigned int* aggX = (unsigned int*)take((size_t)NN * 96 * 4);
  char* P1 = take((size_t)NN * 256 * 2);
  char* P0 = take((size_t)NN * 256 * 2);

  unsigned short* h1raw = (unsigned short*)P1;  // [NN][256] bf16
  unsigned short* z2    = (unsigned short*)P0;  // [NN][256] bf16
  unsigned short* h2raw = (unsigned short*)P1;  // [NN][128] bf16
  unsigned short* z3    = (unsigned short*)P0;  // [NN][128] bf16

  float* logits = (float*)d_out;
  float* emb    = (float*)d_out + (size_t)NN * 2;

  hipMemsetAsync(bkt_cur, 0, 1024, stream);

  // fused front: bpart + prep_x + pack_w + bnacc zero
  {
    int grid = BPART_BLKS + PREP_BLKS + PACK_BLKS + 4;
    k_front<<<grid, 256, 0, stream>>>(src, dst, bkt_cur, pairs, x, xbu, aggX,
                                      Wl1, Wr1, Wl2, Wr2, Wle, Wre, w1c, w2s, w3s, bnacc1);
  }
  k_bscatter<<<NB, NB, 0, stream>>>(pairs, bkt_cur, begend, col);

  // ---- layer 1: aggX = agg(xbu); h1raw = [aggX | xbu] @ w1c + b1 (+BN stats) ----
  k_aggb<166, 4, false, true, false><<<(NN + 3) / 4, 256, 0, stream>>>(
      xbu, 96, begend, col, nullptr, 0, nullptr, aggX, 96, nullptr, nullptr, nullptr);
  {
    dim3 g((NN + 127) / 128, 2);
    k_gemm_mfma<true, true><<<g, 256, 0, stream>>>(
        (const unsigned short*)aggX, (const unsigned short*)xbu, 192, 192, 384,
        w1c, b1, h1raw, 256, bnacc1);
  }
  k_scsh<256><<<1, 256, 0, stream>>>(bnacc1, g1, bt1, scsh1);

  // ---- layer 2: z2 = BN1(h1raw) @ [Wl2;Wr2]^T (BN fused in A-staging);
  //      h2raw = agg(z2[:,:128]) + z2[:,128:] + b2 (bf16 out) ----
  {
    dim3 g((NN + 127) / 128, 2);
    k_gemm_bn<<<g, 256, 0, stream>>>(h1raw, scsh1, w2s, z2, 256, 256);
  }
  k_aggb<128, 8, true, true, false><<<(NN + 3) / 4, 256, 0, stream>>>(
      (const unsigned int*)z2, 128, begend, col, (const unsigned int*)z2 + 64, 128, b2,
      h2raw, 64, nullptr, nullptr, nullptr);
  k_bn_stats2<128, true><<<512, 256, 0, stream>>>(h2raw, bnacc2);
  k_scsh<128><<<1, 128, 0, stream>>>(bnacc2, g2, bt2, scsh2);

  // ---- layer 3: z3 = BN2(h2raw) @ [Wle;Wre]^T; emb = agg(z3[:,:64]) + z3[:,64:] + be ----
  {
    dim3 g((NN + 127) / 128, 1);
    k_gemm_bn<<<g, 256, 0, stream>>>(h2raw, scsh2, w3s, z3, 128, 128);
  }
  k_aggb<64, 8, true, false, true><<<(NN + 7) / 8, 256, 0, stream>>>(
      (const unsigned int*)z3, 64, begend, col, (const unsigned int*)z3 + 32, 64, be,
      emb, 64, Wc, bc, logits);
}

// Round 21
// 272.660 us; speedup vs baseline: 1.0357x; 1.0039x over previous
//
#include <hip/hip_runtime.h>

#define NN 50000
#define NE 800000
#define NB 256
#define BNODES ((NN + NB - 1) / NB)  // 196 nodes per bucket
#define CAP 4096                     // bucket window capacity (mean 3125, +17 sigma)
#define BPART_BLKS ((NE + 8191) / 8192)          // 98
#define PREP_BLKS ((NN * 32 + 255) / 256)        // 6250
#define PACK_BLKS ((180224 + 255) / 256)         // 704
static constexpr float BN_EPS = 1e-5f;

typedef __attribute__((ext_vector_type(8))) short bf16x8;
typedef __attribute__((ext_vector_type(4))) float f32x4;

__device__ inline unsigned short f2bf(float f) {
  unsigned int u = __float_as_uint(f);
  return (unsigned short)((u + 0x7FFFu + ((u >> 16) & 1u)) >> 16);
}
__device__ inline float bf2f(unsigned int h) { return __uint_as_float(h << 16); }
__device__ inline void gl_lds16(const char* g, char* l) {
  __builtin_amdgcn_global_load_lds((const __attribute__((address_space(1))) void*)g,
                                   (__attribute__((address_space(3))) void*)l, 16, 0, 0);
}

// ========== fused front kernel: bpart | prep_x (shift-indexed uint4) | pack_w | bnacc zero ==========
__device__ void dev_bpart(int bb, const int* __restrict__ src, const int* __restrict__ dst,
                          int* __restrict__ bcur, uint2* __restrict__ pairs) {
  __shared__ int cnt[NB], lbase[NB], lcur[NB];
  int t = threadIdx.x;
  cnt[t] = 0;
  __syncthreads();
  int e0 = bb * 8192 + t;
#pragma unroll
  for (int i = 0; i < 32; ++i) {
    int e = e0 + i * 256;
    if (e < NE) atomicAdd(&cnt[dst[e] / BNODES], 1);
  }
  __syncthreads();
  lbase[t] = cnt[t] ? (t * CAP + atomicAdd(&bcur[t], cnt[t])) : 0;
  lcur[t] = 0;
  __syncthreads();
#pragma unroll
  for (int i = 0; i < 32; ++i) {
    int e = e0 + i * 256;
    if (e < NE) {
      int d = dst[e];
      int b = d / BNODES;
      int p = atomicAdd(&lcur[b], 1);
      pairs[(size_t)lbase[b] + p] = uint2{(unsigned)src[e], (unsigned)d};
    }
  }
}

__global__ void k_front(const int* __restrict__ src, const int* __restrict__ dst,
                        int* __restrict__ bcur, uint2* __restrict__ pairs,
                        const float* __restrict__ x, unsigned int* __restrict__ xbu,
                        unsigned int* __restrict__ aggX,
                        const float* __restrict__ Wl1, const float* __restrict__ Wr1,
                        const float* __restrict__ Wl2, const float* __restrict__ Wr2,
                        const float* __restrict__ Wle, const float* __restrict__ Wre,
                        unsigned short* __restrict__ w1c, unsigned short* __restrict__ w2s,
                        unsigned short* __restrict__ w3s,
                        float* __restrict__ bnacc) {
  int b = blockIdx.x;
  if (b < BPART_BLKS) {
    dev_bpart(b, src, dst, bcur, pairs);
    return;
  }
  b -= BPART_BLKS;
  if (b < PREP_BLKS) {
    int i = b * 256 + threadIdx.x;
    int r = i >> 5, q = i & 31;  // 32 slots/row, shift-indexed (no int division)
    if (r >= NN) return;
    if (q < 24) {  // xbu uint4 q: uints 4q..4q+3 = bf16 cols 8q..8q+7
      uint4 o = {0u, 0u, 0u, 0u};
      if (q < 21) {
        const float* xp = x + (size_t)r * 166 + 8 * q;
        unsigned int* ou = (unsigned int*)&o;
#pragma unroll
        for (int j = 0; j < 4; ++j) {
          int c = 8 * q + 2 * j;
          if (c + 1 < 166) {
            float2 v = *reinterpret_cast<const float2*>(xp + 2 * j);
            ou[j] = (unsigned)f2bf(v.x) | ((unsigned)f2bf(v.y) << 16);
          }
        }
      }
      reinterpret_cast<uint4*>(xbu)[(size_t)r * 24 + q] = o;
    } else if (q < 28) {  // aggX pad uint4s: uints 80..95 (agg later overwrites 80..82)
      int j = q - 24;
      reinterpret_cast<uint4*>(aggX)[(size_t)r * 24 + 20 + j] = uint4{0u, 0u, 0u, 0u};
    }
    return;
  }
  b -= PREP_BLKS;
  if (b < PACK_BLKS) {
    int idx = b * 256 + threadIdx.x;
    if (idx < 98304) {  // w1c [256][384]
      int n = idx / 384, k = idx - n * 384;
      float v = 0.f;
      if (k < 166) v = Wl1[(size_t)n * 166 + k];
      else if (k >= 192 && k < 358) v = Wr1[(size_t)n * 166 + (k - 192)];
      w1c[idx] = f2bf(v);
    } else if (idx < 163840) {  // w2s [256][256]
      int j = idx - 98304;
      int n = j / 256, k = j - n * 256;
      w2s[j] = f2bf(n < 128 ? Wl2[(size_t)n * 256 + k] : Wr2[(size_t)(n - 128) * 256 + k]);
    } else if (idx < 180224) {  // w3s [128][128]
      int j = idx - 163840;
      int n = j / 128, k = j - n * 128;
      w3s[j] = f2bf(n < 64 ? Wle[(size_t)n * 128 + k] : Wre[(size_t)(n - 64) * 128 + k]);
    }
    return;
  }
  int z = (b - PACK_BLKS) * 256 + threadIdx.x;
  if (z < 1024) bnacc[z] = 0.f;
}

// ================= per-bucket scatter: begend + col =================
__global__ void k_bscatter(const uint2* __restrict__ pairs, const int* __restrict__ bcur,
                           int2* __restrict__ begend, int* __restrict__ col) {
  __shared__ int dcnt[NB], ts[NB], doff[NB], dcur[NB];
  int t = threadIdx.x;
  int b = blockIdx.x;
  int n0 = b * BNODES;
  int ncnt = min(NN - n0, BNODES);
  int e0 = b * CAP, e1 = e0 + bcur[b];
  dcnt[t] = 0;
  __syncthreads();
  for (int e = e0 + t; e < e1; e += 256) atomicAdd(&dcnt[pairs[e].y - n0], 1);
  __syncthreads();
  ts[t] = dcnt[t];
  __syncthreads();
#pragma unroll
  for (int off = 1; off < NB; off <<= 1) {
    int u = (t >= off) ? ts[t - off] : 0;
    __syncthreads();
    ts[t] += u;
    __syncthreads();
  }
  doff[t] = ts[t] - dcnt[t];
  dcur[t] = 0;
  if (t < ncnt) begend[n0 + t] = int2{e0 + doff[t], e0 + doff[t] + dcnt[t]};
  __syncthreads();
  for (int e = e0 + t; e < e1; e += 256) {
    uint2 pr = pairs[e];
    int ld = pr.y - n0;
    int p = atomicAdd(&dcur[ld], 1);
    col[e0 + doff[ld] + p] = (int)pr.x;
  }
}

// ================= bf16 mean aggregation (begend CSR) =================
template <int D, int U, bool FUSE, bool OUTBF, bool CLS>
__global__ __launch_bounds__(256) void k_aggb(
    const unsigned int* __restrict__ feat, int fsu,
    const int2* __restrict__ begend, const int* __restrict__ col,
    const unsigned int* __restrict__ self, int ssu,
    const float* __restrict__ bias,
    void* __restrict__ outv, int osu,
    const float* __restrict__ Wc, const float* __restrict__ bc,
    float* __restrict__ logits) {
  constexpr int D2 = D / 2;
  constexpr int LPN = (D2 < 64) ? D2 : 64;
  constexpr int NPB = 256 / LPN;
  constexpr int C = (D2 + LPN - 1) / LPN;
  int node = blockIdx.x * NPB + threadIdx.x / LPN;
  if (node >= NN) return;
  int lane = threadIdx.x % LPN;
  int2 be = begend[node];
  int beg = be.x, end = be.y;
  float ax[C], ay[C];
#pragma unroll
  for (int c = 0; c < C; ++c) { ax[c] = 0.f; ay[c] = 0.f; }

  int j = beg;
  for (; j + U <= end; j += U) {
    const unsigned int* fp[U];
#pragma unroll
    for (int u = 0; u < U; ++u) fp[u] = feat + (size_t)col[j + u] * fsu;
#pragma unroll
    for (int c = 0; c < C; ++c) {
      int p = lane + c * LPN;
      unsigned int t[U];
#pragma unroll
      for (int u = 0; u < U; ++u) t[u] = (p < D2) ? fp[u][p] : 0u;
#pragma unroll
      for (int u = 0; u < U; ++u) {
        ax[c] += bf2f(t[u] & 0xffffu);
        ay[c] += bf2f(t[u] >> 16);
      }
    }
  }
  for (; j < end; ++j) {
    const unsigned int* fr = feat + (size_t)col[j] * fsu;
#pragma unroll
    for (int c = 0; c < C; ++c) {
      int p = lane + c * LPN;
      if (p < D2) {
        unsigned int t = fr[p];
        ax[c] += bf2f(t & 0xffffu);
        ay[c] += bf2f(t >> 16);
      }
    }
  }
  float inv = 1.0f / fmaxf((float)(end - beg), 1.0f);
  float s0 = 0.f, s1 = 0.f;
#pragma unroll
  for (int c = 0; c < C; ++c) {
    int p = lane + c * LPN;
    if (p < D2) {
      float vx = ax[c] * inv, vy = ay[c] * inv;
      if constexpr (FUSE) {
        unsigned int s = self[(size_t)node * ssu + p];
        vx += bf2f(s & 0xffffu) + bias[2 * p];
        vy += bf2f(s >> 16) + bias[2 * p + 1];
      }
      if constexpr (OUTBF) {
        unsigned int o = (unsigned int)f2bf(vx) | ((unsigned int)f2bf(vy) << 16);
        ((unsigned int*)outv)[(size_t)node * osu + p] = o;
      } else {
        float2 o{vx, vy};
        *reinterpret_cast<float2*>((float*)outv + (size_t)node * osu + 2 * p) = o;
      }
      if constexpr (CLS) {
        s0 += vx * Wc[2 * p] + vy * Wc[2 * p + 1];
        s1 += vx * Wc[64 + 2 * p] + vy * Wc[64 + 2 * p + 1];
      }
    }
  }
  if constexpr (CLS) {
#pragma unroll
    for (int m = 1; m < LPN; m <<= 1) {
      s0 += __shfl_xor(s0, m);
      s1 += __shfl_xor(s1, m);
    }
    if (lane == 0) {
      logits[node * 2 + 0] = s0 + bc[0];
      logits[node * 2 + 1] = s1 + bc[1];
    }
  }
}

// ===== GEMM1 (counted-vmcnt): 128x128, BK=64, 2x32KB dbuf, A split at K1, bias+stats =====
template <bool BIASED, bool STATS>
__global__ __launch_bounds__(256) void k_gemm_mfma(
    const unsigned short* __restrict__ A0, const unsigned short* __restrict__ A1,
    int K1, int Astride, int KC,
    const unsigned short* __restrict__ W,
    const float* __restrict__ bias,
    unsigned short* __restrict__ out, int Ntot,
    float* __restrict__ statacc) {
  __shared__ __align__(16) char lds[65536];
  int tid = threadIdx.x;
  int lane = tid & 63;
  int w = tid >> 6;
  int wr = w >> 1, wc = w & 1;
  int m0 = blockIdx.x * 128;
  int n0 = blockIdx.y * 128;

  int srow = lane >> 3;
  int scol = (lane & 7) << 4;
  int ssw = scol ^ (srow << 4);
  const char* Wb = (const char*)W;

  f32x4 acc[4][4];
#pragma unroll
  for (int i = 0; i < 4; ++i)
#pragma unroll
    for (int j = 0; j < 4; ++j) acc[i][j] = f32x4{0.f, 0.f, 0.f, 0.f};

  auto stage = [&](int buf, int k0) {
    const char* Ab = (const char*)(k0 < K1 ? A0 : A1);
    int koff = k0 < K1 ? k0 : k0 - K1;
    char* dst = lds + buf * 32768 + w * 4096;
#pragma unroll
    for (int i = 0; i < 4; ++i) {
      int row = w * 32 + i * 8 + srow;
      int ga = m0 + row;
      ga = ga < NN ? ga : NN - 1;
      gl_lds16(Ab + ((size_t)ga * Astride + koff) * 2 + ssw, dst + i * 1024);
      gl_lds16(Wb + ((size_t)(n0 + row) * KC + k0) * 2 + ssw, dst + 16384 + i * 1024);
    }
  };
  auto compute = [&](int buf) {
    char* lA = lds + buf * 32768;
    char* lB = lA + 16384;
#pragma unroll
    for (int ks = 0; ks < 2; ++ks) {
      bf16x8 af[4], bfr[4];
      int ac = ks * 64 + ((lane >> 4) << 4);
#pragma unroll
      for (int f = 0; f < 4; ++f) {
        int ar = wr * 64 + f * 16 + (lane & 15);
        af[f] = *reinterpret_cast<const bf16x8*>(lA + ar * 128 + (ac ^ ((ar & 7) << 4)));
        int br = wc * 64 + f * 16 + (lane & 15);
        bfr[f] = *reinterpret_cast<const bf16x8*>(lB + br * 128 + (ac ^ ((br & 7) << 4)));
      }
#pragma unroll
      for (int fm = 0; fm < 4; ++fm)
#pragma unroll
        for (int fn = 0; fn < 4; ++fn)
          acc[fm][fn] = __builtin_amdgcn_mfma_f32_16x16x32_bf16(af[fm], bfr[fn], acc[fm][fn], 0, 0, 0);
    }
  };

  int nt = KC >> 6;
  stage(0, 0);
  if (nt > 1) stage(1, 64);
  for (int t = 0; t < nt - 1; ++t) {
    asm volatile("s_waitcnt vmcnt(8)" ::: "memory");
    __builtin_amdgcn_s_barrier();
    compute(t & 1);
    __builtin_amdgcn_s_barrier();
    if (t + 2 < nt) stage(t & 1, (t + 2) << 6);
  }
  asm volatile("s_waitcnt vmcnt(0)" ::: "memory");
  __builtin_amdgcn_s_barrier();
  compute((nt - 1) & 1);

  int nbase = n0 + wc * 64 + (lane & 15);
  float bv[4] = {0.f, 0.f, 0.f, 0.f};
  if constexpr (BIASED) {
#pragma unroll
    for (int fn = 0; fn < 4; ++fn) bv[fn] = bias[nbase + fn * 16];
  }
  float ssum[4] = {0.f, 0.f, 0.f, 0.f}, sqs[4] = {0.f, 0.f, 0.f, 0.f};
#pragma unroll
  for (int fm = 0; fm < 4; ++fm) {
    int mbase = m0 + wr * 64 + fm * 16 + ((lane >> 4) << 2);
#pragma unroll
    for (int j = 0; j < 4; ++j) {
      int m = mbase + j;
      if (m < NN) {
#pragma unroll
        for (int fn = 0; fn < 4; ++fn) {
          float v = acc[fm][fn][j] + bv[fn];
          out[(size_t)m * Ntot + nbase + fn * 16] = f2bf(v);
          if constexpr (STATS) { ssum[fn] += v; sqs[fn] += v * v; }
        }
      }
    }
  }
  if constexpr (STATS) {
#pragma unroll
    for (int fn = 0; fn < 4; ++fn) {
      float s = ssum[fn], q = sqs[fn];
      s += __shfl_xor(s, 16); s += __shfl_xor(s, 32);
      q += __shfl_xor(q, 16); q += __shfl_xor(q, 32);
      if (lane < 16) {
        atomicAdd(&statacc[nbase + fn * 16], s);
        atomicAdd(&statacc[Ntot + nbase + fn * 16], q);
      }
    }
  }
}

// ===== GEMM with fused BN+ReLU on A (layers 2,3): A reg-staged + transformed, W gl_lds =====
// BN scale/shift computed inline from bnacc/gamma/beta (k_scsh dispatch eliminated).
__global__ __launch_bounds__(256) void k_gemm_bn(
    const unsigned short* __restrict__ A,
    const float* __restrict__ bnacc, const float* __restrict__ gamma,
    const float* __restrict__ beta, int Nbn,
    const unsigned short* __restrict__ W,
    unsigned short* __restrict__ out, int KC, int Ntot) {
  __shared__ __align__(16) char lds[65536];
  int tid = threadIdx.x;
  int lane = tid & 63;
  int w = tid >> 6;
  int wr = w >> 1, wc = w & 1;
  int m0 = blockIdx.x * 128;
  int n0 = blockIdx.y * 128;

  int srow = lane >> 3;
  int cb = (lane & 7) << 4;
  int ssw = cb ^ (srow << 4);
  int kk0 = (lane & 7) << 3;
  const char* Wb = (const char*)W;

  f32x4 acc[4][4];
#pragma unroll
  for (int i = 0; i < 4; ++i)
#pragma unroll
    for (int j = 0; j < 4; ++j) acc[i][j] = f32x4{0.f, 0.f, 0.f, 0.f};

  uint4 areg[4];
  float4 sc[4];

  auto loadA = [&](int k0) {
    int kk = k0 + kk0;
#pragma unroll
    for (int u = 0; u < 4; ++u) {
      int c0 = kk + 2 * u, c1 = c0 + 1;
      float m0f = bnacc[c0] * (1.0f / NN), m1f = bnacc[c1] * (1.0f / NN);
      float s0 = gamma[c0] * rsqrtf(bnacc[Nbn + c0] * (1.0f / NN) - m0f * m0f + BN_EPS);
      float s1 = gamma[c1] * rsqrtf(bnacc[Nbn + c1] * (1.0f / NN) - m1f * m1f + BN_EPS);
      sc[u] = float4{s0, beta[c0] - m0f * s0, s1, beta[c1] - m1f * s1};
    }
#pragma unroll
    for (int i = 0; i < 4; ++i) {
      int row = w * 32 + i * 8 + srow;
      int ga = m0 + row;
      ga = ga < NN ? ga : NN - 1;
      areg[i] = *reinterpret_cast<const uint4*>(A + (size_t)ga * KC + kk);
    }
  };
  auto writeA = [&](int buf) {
    char* dstb = lds + buf * 32768;
#pragma unroll
    for (int i = 0; i < 4; ++i) {
      int row = w * 32 + i * 8 + srow;
      uint4 v = areg[i], o;
      float a, b;
      a = fmaxf(bf2f(v.x & 0xffffu) * sc[0].x + sc[0].y, 0.f);
      b = fmaxf(bf2f(v.x >> 16)     * sc[0].z + sc[0].w, 0.f);
      o.x = (unsigned)f2bf(a) | ((unsigned)f2bf(b) << 16);
      a = fmaxf(bf2f(v.y & 0xffffu) * sc[1].x + sc[1].y, 0.f);
      b = fmaxf(bf2f(v.y >> 16)     * sc[1].z + sc[1].w, 0.f);
      o.y = (unsigned)f2bf(a) | ((unsigned)f2bf(b) << 16);
      a = fmaxf(bf2f(v.z & 0xffffu) * sc[2].x + sc[2].y, 0.f);
      b = fmaxf(bf2f(v.z >> 16)     * sc[2].z + sc[2].w, 0.f);
      o.z = (unsigned)f2bf(a) | ((unsigned)f2bf(b) << 16);
      a = fmaxf(bf2f(v.w & 0xffffu) * sc[3].x + sc[3].y, 0.f);
      b = fmaxf(bf2f(v.w >> 16)     * sc[3].z + sc[3].w, 0.f);
      o.w = (unsigned)f2bf(a) | ((unsigned)f2bf(b) << 16);
      *reinterpret_cast<uint4*>(dstb + row * 128 + (cb ^ ((row & 7) << 4))) = o;
    }
  };
  auto stageW = [&](int buf, int k0) {
    char* dst = lds + buf * 32768 + 16384 + w * 4096;
#pragma unroll
    for (int i = 0; i < 4; ++i) {
      int row = w * 32 + i * 8 + srow;
      gl_lds16(Wb + ((size_t)(n0 + row) * KC + k0) * 2 + ssw, dst + i * 1024);
    }
  };
  auto compute = [&](int buf) {
    char* lA = lds + buf * 32768;
    char* lB = lA + 16384;
#pragma unroll
    for (int ks = 0; ks < 2; ++ks) {
      bf16x8 af[4], bfr[4];
      int ac = ks * 64 + ((lane >> 4) << 4);
#pragma unroll
      for (int f = 0; f < 4; ++f) {
        int ar = wr * 64 + f * 16 + (lane & 15);
        af[f] = *reinterpret_cast<const bf16x8*>(lA + ar * 128 + (ac ^ ((ar & 7) << 4)));
        int br = wc * 64 + f * 16 + (lane & 15);
        bfr[f] = *reinterpret_cast<const bf16x8*>(lB + br * 128 + (ac ^ ((br & 7) << 4)));
      }
#pragma unroll
      for (int fm = 0; fm < 4; ++fm)
#pragma unroll
        for (int fn = 0; fn < 4; ++fn)
          acc[fm][fn] = __builtin_amdgcn_mfma_f32_16x16x32_bf16(af[fm], bfr[fn], acc[fm][fn], 0, 0, 0);
    }
  };

  int nt = KC >> 6;  // 4 / 2
  loadA(0);
  stageW(0, 0);
  writeA(0);
  __syncthreads();
  int cur = 0;
  for (int t = 0; t < nt; ++t) {
    if (t + 1 < nt) { loadA((t + 1) << 6); stageW(cur ^ 1, (t + 1) << 6); }
    compute(cur);
    __syncthreads();
    if (t + 1 < nt) writeA(cur ^ 1);
    __syncthreads();
    cur ^= 1;
  }

  int nbase = n0 + wc * 64 + (lane & 15);
#pragma unroll
  for (int fm = 0; fm < 4; ++fm) {
    int mbase = m0 + wr * 64 + fm * 16 + ((lane >> 4) << 2);
#pragma unroll
    for (int j = 0; j < 4; ++j) {
      int m = mbase + j;
      if (m < NN) {
#pragma unroll
        for (int fn = 0; fn < 4; ++fn)
          out[(size_t)m * Ntot + nbase + fn * 16] = f2bf(acc[fm][fn][j]);
      }
    }
  }
}

// ================= BN stats (layer 2) =================
template <int N, bool BF>
__global__ __launch_bounds__(256) void k_bn_stats2(const void* __restrict__ hv,
                                                   float* __restrict__ acc) {
  constexpr int CP = N / 2;
  constexpr int RG = 256 / CP;
  int cp = threadIdx.x % CP, rg = threadIdx.x / CP;
  int rpb = (NN + gridDim.x - 1) / gridDim.x;
  int r0 = blockIdx.x * rpb, r1 = min(r0 + rpb, NN);
  float s0 = 0.f, s1 = 0.f, q0 = 0.f, q1 = 0.f;
  for (int r = r0 + rg; r < r1; r += RG) {
    float v0, v1;
    if constexpr (BF) {
      unsigned int u = ((const unsigned int*)hv)[(size_t)r * CP + cp];
      v0 = bf2f(u & 0xffffu); v1 = bf2f(u >> 16);
    } else {
      float2 u = ((const float2*)hv)[(size_t)r * CP + cp];
      v0 = u.x; v1 = u.y;
    }
    s0 += v0; s1 += v1; q0 += v0 * v0; q1 += v1 * v1;
  }
  __shared__ float l0[256], l1[256], l2[256], l3[256];
  l0[threadIdx.x] = s0; l1[threadIdx.x] = s1; l2[threadIdx.x] = q0; l3[threadIdx.x] = q1;
  __syncthreads();
  if (rg == 0) {
#pragma unroll
    for (int g = 1; g < RG; ++g) {
      s0 += l0[g * CP + cp]; s1 += l1[g * CP + cp];
      q0 += l2[g * CP + cp]; q1 += l3[g * CP + cp];
    }
    atomicAdd(&acc[2 * cp], s0);
    atomicAdd(&acc[2 * cp + 1], s1);
    atomicAdd(&acc[N + 2 * cp], q0);
    atomicAdd(&acc[N + 2 * cp + 1], q1);
  }
}

extern "C" void kernel_launch(void* const* d_in, const int* in_sizes, int n_in,
                              void* d_out, int out_size, void* d_ws, size_t ws_size,
                              hipStream_t stream) {
  const float* x   = (const float*)d_in[0];
  const int* ei    = (const int*)d_in[1];
  const float* Wl1 = (const float*)d_in[2];
  const float* Wr1 = (const float*)d_in[3];
  const float* b1  = (const float*)d_in[4];
  const float* Wl2 = (const float*)d_in[5];
  const float* Wr2 = (const float*)d_in[6];
  const float* b2  = (const float*)d_in[7];
  const float* Wle = (const float*)d_in[8];
  const float* Wre = (const float*)d_in[9];
  const float* be  = (const float*)d_in[10];
  const float* g1  = (const float*)d_in[11];
  const float* bt1 = (const float*)d_in[12];
  const float* g2  = (const float*)d_in[13];
  const float* bt2 = (const float*)d_in[14];
  const float* Wc  = (const float*)d_in[15];
  const float* bc  = (const float*)d_in[16];

  const int* src = ei;
  const int* dst = ei + NE;

  char* ws = (char*)d_ws;
  size_t off = 0;
  auto take = [&](size_t bytes) -> char* {
    char* p = ws + off;
    off = (off + bytes + 255) & ~(size_t)255;
    return p;
  };
  int* bkt_cur   = (int*)take(1024);
  float* bnacc1  = (float*)take(2048);   // zeroed by k_front tail blocks
  float* bnacc2  = (float*)take(2048);
  int2* begend   = (int2*)take((size_t)NN * 8);
  uint2* pairs   = (uint2*)take((size_t)NB * CAP * 8);
  int* col       = (int*)take((size_t)NB * CAP * 4);
  unsigned short* w1c = (unsigned short*)take((size_t)256 * 384 * 2);
  unsigned short* w2s = (unsigned short*)take((size_t)256 * 256 * 2);
  unsigned short* w3s = (unsigned short*)take((size_t)128 * 128 * 2);
  unsigned int* xbu  = (unsigned int*)take((size_t)NN * 96 * 4);
  unsigned int* aggX = (unsigned int*)take((size_t)NN * 96 * 4);
  char* P1 = take((size_t)NN * 256 * 2);
  char* P0 = take((size_t)NN * 256 * 2);

  unsigned short* h1raw = (unsigned short*)P1;  // [NN][256] bf16
  unsigned short* z2    = (unsigned short*)P0;  // [NN][256] bf16
  unsigned short* h2raw = (unsigned short*)P1;  // [NN][128] bf16
  unsigned short* z3    = (unsigned short*)P0;  // [NN][128] bf16

  float* logits = (float*)d_out;
  float* emb    = (float*)d_out + (size_t)NN * 2;

  hipMemsetAsync(bkt_cur, 0, 1024, stream);

  // fused front: bpart + prep_x + pack_w + bnacc zero
  {
    int grid = BPART_BLKS + PREP_BLKS + PACK_BLKS + 4;
    k_front<<<grid, 256, 0, stream>>>(src, dst, bkt_cur, pairs, x, xbu, aggX,
                                      Wl1, Wr1, Wl2, Wr2, Wle, Wre, w1c, w2s, w3s, bnacc1);
  }
  k_bscatter<<<NB, NB, 0, stream>>>(pairs, bkt_cur, begend, col);

  // ---- layer 1: aggX = agg(xbu); h1raw = [aggX | xbu] @ w1c + b1 (+BN stats) ----
  k_aggb<166, 4, false, true, false><<<(NN + 3) / 4, 256, 0, stream>>>(
      xbu, 96, begend, col, nullptr, 0, nullptr, aggX, 96, nullptr, nullptr, nullptr);
  {
    dim3 g((NN + 127) / 128, 2);
    k_gemm_mfma<true, true><<<g, 256, 0, stream>>>(
        (const unsigned short*)aggX, (const unsigned short*)xbu, 192, 192, 384,
        w1c, b1, h1raw, 256, bnacc1);
  }

  // ---- layer 2: z2 = BN1(h1raw) @ [Wl2;Wr2]^T (BN inline from bnacc1);
  //      h2raw = agg(z2[:,:128]) + z2[:,128:] + b2 (bf16 out) ----
  {
    dim3 g((NN + 127) / 128, 2);
    k_gemm_bn<<<g, 256, 0, stream>>>(h1raw, bnacc1, g1, bt1, 256, w2s, z2, 256, 256);
  }
  k_aggb<128, 8, true, true, false><<<(NN + 3) / 4, 256, 0, stream>>>(
      (const unsigned int*)z2, 128, begend, col, (const unsigned int*)z2 + 64, 128, b2,
      h2raw, 64, nullptr, nullptr, nullptr);
  k_bn_stats2<128, true><<<512, 256, 0, stream>>>(h2raw, bnacc2);

  // ---- layer 3: z3 = BN2(h2raw) @ [Wle;Wre]^T (BN inline from bnacc2);
  //      emb = agg(z3[:,:64]) + z3[:,64:] + be; fused classifier ----
  {
    dim3 g((NN + 127) / 128, 1);
    k_gemm_bn<<<g, 256, 0, stream>>>(h2raw, bnacc2, g2, bt2, 128, w3s, z3, 128, 128);
  }
  k_aggb<64, 8, true, false, true><<<(NN + 7) / 8, 256, 0, stream>>>(
      (const unsigned int*)z3, 64, begend, col, (const unsigned int*)z3 + 32, 64, be,
      emb, 64, Wc, bc, logits);
}